// Round 2
// baseline (121.059 us; speedup 1.0000x reference)
//
#include <hip/hip_runtime.h>

#define BATCH   8
#define VIN     4096
#define CIN     64
#define VOUTN   16384
#define SN      9
#define COUT    32
#define VT      64   // v-positions per dwpw block
#define UPB     64   // u-positions per pool block

typedef float f32x4 __attribute__((ext_vector_type(4)));  // for nontemporal builtins

// bf16 <-> f32 (RNE) via bit ops
__device__ __forceinline__ unsigned short f2bf(float f) {
  unsigned u = __float_as_uint(f);
  u += 0x7FFFu + ((u >> 16) & 1u);
  return (unsigned short)(u >> 16);
}
__device__ __forceinline__ float bf2f(unsigned short h) {
  return __uint_as_float((unsigned)h << 16);
}

// Kernel 1: pooled[b,u,c] = sum_{j<3} tv[e_j] * x[b, tc[e_j], c]  -> bf16
// XCD-pinned batch = blockIdx & 7. UPB=64: 2048 blocks, 12 gathers in flight/thread.
__global__ __launch_bounds__(256) void pool_kernel(
    const float* __restrict__ x, const int* __restrict__ trans_col,
    const float* __restrict__ trans_value, const int* __restrict__ row_map,
    unsigned short* __restrict__ pooled) {
  __shared__ int   scol[UPB * 3];
  __shared__ float sval[UPB * 3];
  int t  = threadIdx.x;
  int b  = blockIdx.x & 7;                  // XCD-pinned batch
  int u0 = (blockIdx.x >> 3) * UPB;
  if (t < UPB * 3) {                        // 192 threads stage edge metadata
    int e   = row_map[u0 * 3 + t];          // contiguous
    scol[t] = trans_col[e];
    sval[t] = trans_value[e];
  }
  __syncthreads();
  int g = t >> 4, l = t & 15;               // 16 u-groups x 16 lanes (float4 = 256B row)
  const float4* xb4 = (const float4*)(x + (size_t)b * VIN * CIN);
  unsigned short* pb = pooled + (size_t)((b << 14) + u0) * CIN;
#pragma unroll
  for (int k = 0; k < UPB / 16; ++k) {      // 4 u-groups per thread: 12 indep gathers
    int ug = g + k * 16;
    float4 acc = make_float4(0.f, 0.f, 0.f, 0.f);
#pragma unroll
    for (int j = 0; j < 3; ++j) {
      int   col = scol[ug * 3 + j];         // LDS broadcast
      float tv  = sval[ug * 3 + j];
      float4 p  = xb4[col * 16 + l];        // L2-resident (1 MiB x-slice per XCD)
      acc.x += tv * p.x; acc.y += tv * p.y; acc.z += tv * p.z; acc.w += tv * p.w;
    }
    ushort4 h;
    h.x = f2bf(acc.x); h.y = f2bf(acc.y); h.z = f2bf(acc.z); h.w = f2bf(acc.w);
    ((ushort4*)(pb + (size_t)ug * CIN))[l] = h;   // 128B row, full-line writes
  }
}

// Kernel 2: 64 v's per block, XCD-pinned batch.
//  Phase A (16 lanes x 4ch): dw[vl][c] = bd[c] + sum_s Wd[c,s]*pooled_bf16[b,idx[v,s],c]
//  Phase B (lane=vl, wave w -> o in [8w,8w+8)): out = relu(dw . Wp^T + bp)
__global__ __launch_bounds__(256) void dwpw_kernel(
    const unsigned short* __restrict__ pooled, const int* __restrict__ indices,
    const float* __restrict__ Wd, const float* __restrict__ bd,
    const float* __restrict__ Wp, const float* __restrict__ bp,
    float* __restrict__ out) {
  __shared__ float dw[VT][68];              // 68: 16B-aligned rows, (vl+q)%8 quad spread
  __shared__ int   sidx[VT * SN];           // this block's 576 gather indices
  int t  = threadIdx.x;
  int b  = blockIdx.x & 7;                  // XCD-pinned batch
  int v0 = (blockIdx.x >> 3) * VT;

  for (int i = t; i < VT * SN; i += 256)    // 576 coalesced index loads
    sidx[i] = indices[v0 * SN + i];

  // ---- Wd direct to regs (no LDS staging): rows c4..c4+3, reg-transpose ----
  int g = t >> 4, l = t & 15, c4 = l * 4;
  float wflat[36];
#pragma unroll
  for (int q = 0; q < 9; ++q)               // 9 aligned float4s = 36 contiguous floats
    *(float4*)&wflat[q * 4] = *(const float4*)&Wd[c4 * SN + q * 4];
  float4 wd4[SN];
#pragma unroll
  for (int s = 0; s < SN; ++s)              // compile-time indices: pure reg renaming
    wd4[s] = make_float4(wflat[s], wflat[9 + s], wflat[18 + s], wflat[27 + s]);
  float4 bd4 = *(const float4*)(bd + c4);
  const ushort4* pb4 = (const ushort4*)(pooled + (size_t)(b << 14) * CIN);
  __syncthreads();

  // ---- Phase A ----
#pragma unroll
  for (int vi = 0; vi < 4; ++vi) {
    int vl = g + vi * 16;
    int us[SN];
#pragma unroll
    for (int s = 0; s < SN; ++s) us[s] = sidx[vl * SN + s];  // batch LDS reads
    float4 acc = bd4;
#pragma unroll
    for (int s = 0; s < SN; ++s) {
      ushort4 h = pb4[us[s] * 16 + l];      // 128B bf16 row gather, L2-resident
      acc.x += wd4[s].x * bf2f(h.x);
      acc.y += wd4[s].y * bf2f(h.y);
      acc.z += wd4[s].z * bf2f(h.z);
      acc.w += wd4[s].w * bf2f(h.w);
    }
    *(float4*)&dw[vl][c4] = acc;            // aligned, quad-spread banks
  }
  __syncthreads();

  // ---- Phase B ----
  int vl = t & 63;
  int w  = t >> 6;
  int ob = __builtin_amdgcn_readfirstlane(w * 8);   // wave-uniform o-block
  const float* wpo = Wp + ob * CIN;
  float acc[8];
#pragma unroll
  for (int oo = 0; oo < 8; ++oo) acc[oo] = bp[ob + oo];
#pragma unroll
  for (int q = 0; q < 16; ++q) {
    float4 d4 = *(const float4*)&dw[vl][q * 4];     // ds_read_b128, conflict-free
#pragma unroll
    for (int oo = 0; oo < 8; ++oo) {
      acc[oo] += d4.x * wpo[oo * CIN + q * 4 + 0];  // scalar (wave-uniform) loads
      acc[oo] += d4.y * wpo[oo * CIN + q * 4 + 1];
      acc[oo] += d4.z * wpo[oo * CIN + q * 4 + 2];
      acc[oo] += d4.w * wpo[oo * CIN + q * 4 + 3];
    }
  }
  float* op = out + (size_t)((b << 14) + v0 + vl) * COUT + ob;
  f32x4 r0 = { fmaxf(acc[0], 0.f), fmaxf(acc[1], 0.f),
               fmaxf(acc[2], 0.f), fmaxf(acc[3], 0.f) };
  f32x4 r1 = { fmaxf(acc[4], 0.f), fmaxf(acc[5], 0.f),
               fmaxf(acc[6], 0.f), fmaxf(acc[7], 0.f) };
  __builtin_nontemporal_store(r0, (f32x4*)op);       // write-once: don't evict pooled
  __builtin_nontemporal_store(r1, (f32x4*)(op + 4));
}

extern "C" void kernel_launch(void* const* d_in, const int* in_sizes, int n_in,
                              void* d_out, int out_size, void* d_ws, size_t ws_size,
                              hipStream_t stream) {
  const float* x    = (const float*)d_in[0];
  const int*   tc   = (const int*)d_in[2];
  const float* tv   = (const float*)d_in[3];
  const int*   rm   = (const int*)d_in[4];
  const int*   idx  = (const int*)d_in[5];
  const float* Wd   = (const float*)d_in[6];
  const float* bd   = (const float*)d_in[7];
  const float* Wp   = (const float*)d_in[8];
  const float* bp   = (const float*)d_in[9];
  float* out = (float*)d_out;
  unsigned short* pooled = (unsigned short*)d_ws;   // 16 MiB bf16

  pool_kernel<<<BATCH * (VOUTN / UPB), 256, 0, stream>>>(x, tc, tv, rm, pooled);
  dwpw_kernel<<<BATCH * (VOUTN / VT), 256, 0, stream>>>(pooled, idx, Wd, bd, Wp, bp, out);
}

// Round 3
// 116.783 us; speedup vs baseline: 1.0366x; 1.0366x over previous
//
#include <hip/hip_runtime.h>

#define BATCH   8
#define VIN     4096
#define CIN     64
#define VOUTN   16384
#define SN      9
#define COUT    32
#define VT      64   // v-positions per dwpw block
#define UPB     16   // u-positions per pool block

// bf16 <-> f32 (RNE) via bit ops
__device__ __forceinline__ unsigned short f2bf(float f) {
  unsigned u = __float_as_uint(f);
  u += 0x7FFFu + ((u >> 16) & 1u);
  return (unsigned short)(u >> 16);
}
__device__ __forceinline__ float bf2f(unsigned short h) {
  return __uint_as_float((unsigned)h << 16);
}

// Kernel 1 (round-0 proven form): pooled[b,u,c] = sum_{j<3} tv[e_j]*x[b,tc[e_j],c] -> bf16
__global__ __launch_bounds__(256) void pool_kernel(
    const float* __restrict__ x, const int* __restrict__ trans_col,
    const float* __restrict__ trans_value, const int* __restrict__ row_map,
    unsigned short* __restrict__ pooled) {
  __shared__ int   scol[UPB * 3];
  __shared__ float sval[UPB * 3];
  int t  = threadIdx.x;
  int b  = blockIdx.x & 7;                  // XCD-pinned batch
  int u0 = (blockIdx.x >> 3) * UPB;
  if (t < UPB * 3) {
    int e   = row_map[u0 * 3 + t];          // contiguous
    scol[t] = trans_col[e];
    sval[t] = trans_value[e];
  }
  __syncthreads();
  int g = t >> 4, l = t & 15;               // 16 u-groups x 16 lanes (float4 = 256B row)
  const float4* xb4 = (const float4*)(x + (size_t)b * VIN * CIN);
  float4 acc = make_float4(0.f, 0.f, 0.f, 0.f);
#pragma unroll
  for (int j = 0; j < 3; ++j) {
    int   col = scol[g * 3 + j];            // LDS broadcast
    float tv  = sval[g * 3 + j];
    float4 p  = xb4[col * 16 + l];          // L2-resident (1 MiB x-slice per XCD)
    acc.x += tv * p.x; acc.y += tv * p.y; acc.z += tv * p.z; acc.w += tv * p.w;
  }
  ushort4 h;
  h.x = f2bf(acc.x); h.y = f2bf(acc.y); h.z = f2bf(acc.z); h.w = f2bf(acc.w);
  ((ushort4*)(pooled + (size_t)((b << 14) + u0 + g) * CIN))[l] = h;  // 128B row
}

// Kernel 2: 64 v's per block, XCD-pinned batch.
//  Phase A (s-major, register-lean): dw[vl][c] = bd[c] + sum_s Wd[c,s]*pooled[idx[v,s],c]
//    4 carried float4 accumulators; Wd fragment re-read per s from LDS (broadcast b128)
//    instead of a 36-VGPR table -> ~50 live VGPRs, target 7 waves/SIMD.
//  Phase B (lane=vl, wave w -> o in [8w,8w+8)): out = relu(dw . Wp^T + bp)
__global__ __launch_bounds__(256) void dwpw_kernel(
    const unsigned short* __restrict__ pooled, const int* __restrict__ indices,
    const float* __restrict__ Wd, const float* __restrict__ bd,
    const float* __restrict__ Wp, const float* __restrict__ bp,
    float* __restrict__ out) {
  __shared__ float dw[VT][68];              // stride 68: b128 quad (17vl+q)%8 uniform -> conflict-free
  __shared__ int   sidx[VT * SN];           // this block's 576 gather indices
  __shared__ float swdT[SN * CIN];          // Wd transposed [s][c] for float4 reads
  int t  = threadIdx.x;
  int b  = blockIdx.x & 7;                  // XCD-pinned batch
  int v0 = (blockIdx.x >> 3) * VT;

  for (int i = t; i < VT * SN; i += 256) {  // 576 coalesced loads each
    sidx[i] = indices[v0 * SN + i];
    int c = i / SN, s = i - c * SN;         // Wd flat idx i = c*SN + s
    swdT[s * CIN + c] = Wd[i];
  }
  __syncthreads();

  // ---- Phase A: s-major ----
  int g = t >> 4, l = t & 15, c4 = l * 4;
  const ushort4* pb4 = (const ushort4*)(pooled + (size_t)(b << 14) * CIN);
  float4 bd4 = *(const float4*)(bd + c4);
  float4 a0 = bd4, a1 = bd4, a2 = bd4, a3 = bd4;   // vl = g, g+16, g+32, g+48
#pragma unroll
  for (int s = 0; s < SN; ++s) {
    float4 w = *(const float4*)&swdT[s * CIN + c4]; // LDS b128, group-broadcast
    int u0 = sidx[(g     ) * SN + s];
    int u1 = sidx[(g + 16) * SN + s];
    int u2 = sidx[(g + 32) * SN + s];
    int u3 = sidx[(g + 48) * SN + s];
    ushort4 h0 = pb4[u0 * 16 + l];          // 4 independent 128B bf16 gathers, L2-resident
    ushort4 h1 = pb4[u1 * 16 + l];
    ushort4 h2 = pb4[u2 * 16 + l];
    ushort4 h3 = pb4[u3 * 16 + l];
    a0.x += w.x * bf2f(h0.x); a0.y += w.y * bf2f(h0.y);
    a0.z += w.z * bf2f(h0.z); a0.w += w.w * bf2f(h0.w);
    a1.x += w.x * bf2f(h1.x); a1.y += w.y * bf2f(h1.y);
    a1.z += w.z * bf2f(h1.z); a1.w += w.w * bf2f(h1.w);
    a2.x += w.x * bf2f(h2.x); a2.y += w.y * bf2f(h2.y);
    a2.z += w.z * bf2f(h2.z); a2.w += w.w * bf2f(h2.w);
    a3.x += w.x * bf2f(h3.x); a3.y += w.y * bf2f(h3.y);
    a3.z += w.z * bf2f(h3.z); a3.w += w.w * bf2f(h3.w);
  }
  *(float4*)&dw[g     ][c4] = a0;           // b128 writes, (g+l)%8 quad spread
  *(float4*)&dw[g + 16][c4] = a1;
  *(float4*)&dw[g + 32][c4] = a2;
  *(float4*)&dw[g + 48][c4] = a3;
  __syncthreads();

  // ---- Phase B ----
  int vl = t & 63;
  int w  = t >> 6;
  int ob = __builtin_amdgcn_readfirstlane(w * 8);   // wave-uniform o-block
  const float* wpo = Wp + ob * CIN;
  float acc[8];
#pragma unroll
  for (int oo = 0; oo < 8; ++oo) acc[oo] = bp[ob + oo];
#pragma unroll
  for (int q = 0; q < 16; ++q) {
    float4 d4 = *(const float4*)&dw[vl][q * 4];     // ds_read_b128, conflict-free
#pragma unroll
    for (int oo = 0; oo < 8; ++oo) {
      acc[oo] += d4.x * wpo[oo * CIN + q * 4 + 0];  // scalar (wave-uniform) loads
      acc[oo] += d4.y * wpo[oo * CIN + q * 4 + 1];
      acc[oo] += d4.z * wpo[oo * CIN + q * 4 + 2];
      acc[oo] += d4.w * wpo[oo * CIN + q * 4 + 3];
    }
  }
  float* op = out + (size_t)((b << 14) + v0 + vl) * COUT + ob;
  float4 r0 = make_float4(fmaxf(acc[0], 0.f), fmaxf(acc[1], 0.f),
                          fmaxf(acc[2], 0.f), fmaxf(acc[3], 0.f));
  float4 r1 = make_float4(fmaxf(acc[4], 0.f), fmaxf(acc[5], 0.f),
                          fmaxf(acc[6], 0.f), fmaxf(acc[7], 0.f));
  *(float4*)op = r0;
  *(float4*)(op + 4) = r1;
}

extern "C" void kernel_launch(void* const* d_in, const int* in_sizes, int n_in,
                              void* d_out, int out_size, void* d_ws, size_t ws_size,
                              hipStream_t stream) {
  const float* x    = (const float*)d_in[0];
  const int*   tc   = (const int*)d_in[2];
  const float* tv   = (const float*)d_in[3];
  const int*   rm   = (const int*)d_in[4];
  const int*   idx  = (const int*)d_in[5];
  const float* Wd   = (const float*)d_in[6];
  const float* bd   = (const float*)d_in[7];
  const float* Wp   = (const float*)d_in[8];
  const float* bp   = (const float*)d_in[9];
  float* out = (float*)d_out;
  unsigned short* pooled = (unsigned short*)d_ws;   // 16 MiB bf16

  pool_kernel<<<BATCH * (VOUTN / UPB), 256, 0, stream>>>(x, tc, tv, rm, pooled);
  dwpw_kernel<<<BATCH * (VOUTN / VT), 256, 0, stream>>>(pooled, idx, Wd, bd, Wp, bp, out);
}

// Round 4
// 113.179 us; speedup vs baseline: 1.0696x; 1.0318x over previous
//
#include <hip/hip_runtime.h>

#define BATCH   8
#define VIN     4096
#define CIN     64
#define VOUTN   16384
#define SN      9
#define COUT    32
#define VT      64   // v-positions per dwpw block
#define UPB     16   // u-positions per pool block

typedef float f32x2 __attribute__((ext_vector_type(2)));
typedef float f32x4 __attribute__((ext_vector_type(4)));

// bf16 <-> f32 (RNE) via bit ops
__device__ __forceinline__ unsigned short f2bf(float f) {
  unsigned u = __float_as_uint(f);
  u += 0x7FFFu + ((u >> 16) & 1u);
  return (unsigned short)(u >> 16);
}

// Kernel 1 (round-0 proven form, untouched): pooled[b,u,c] = sum_j tv*x[b,tc,c] -> bf16
__global__ __launch_bounds__(256) void pool_kernel(
    const float* __restrict__ x, const int* __restrict__ trans_col,
    const float* __restrict__ trans_value, const int* __restrict__ row_map,
    unsigned short* __restrict__ pooled) {
  __shared__ int   scol[UPB * 3];
  __shared__ float sval[UPB * 3];
  int t  = threadIdx.x;
  int b  = blockIdx.x & 7;                  // XCD-pinned batch
  int u0 = (blockIdx.x >> 3) * UPB;
  if (t < UPB * 3) {
    int e   = row_map[u0 * 3 + t];          // contiguous
    scol[t] = trans_col[e];
    sval[t] = trans_value[e];
  }
  __syncthreads();
  int g = t >> 4, l = t & 15;               // 16 u-groups x 16 lanes (float4 = 256B row)
  const float4* xb4 = (const float4*)(x + (size_t)b * VIN * CIN);
  float4 acc = make_float4(0.f, 0.f, 0.f, 0.f);
#pragma unroll
  for (int j = 0; j < 3; ++j) {
    int   col = scol[g * 3 + j];            // LDS broadcast
    float tv  = sval[g * 3 + j];
    float4 p  = xb4[col * 16 + l];          // L2-resident (1 MiB x-slice per XCD)
    acc.x += tv * p.x; acc.y += tv * p.y; acc.z += tv * p.z; acc.w += tv * p.w;
  }
  ushort4 h;
  h.x = f2bf(acc.x); h.y = f2bf(acc.y); h.z = f2bf(acc.z); h.w = f2bf(acc.w);
  ((ushort4*)(pooled + (size_t)((b << 14) + u0 + g) * CIN))[l] = h;  // 128B row
}

// Kernel 2: round-0 structure; VALU-issue cut via packed-pair FMAs.
//  Phase A (vi-major, wd table): dw[vl][c] = bd[c] + sum_s Wd[c,s]*pooled[idx[v,s],c]
//  Phase B: float2 even/odd-channel partials -> v_pk_fma_f32; dw via ds_read_b128.
__global__ __launch_bounds__(256) void dwpw_kernel(
    const unsigned short* __restrict__ pooled, const int* __restrict__ indices,
    const float* __restrict__ Wd, const float* __restrict__ bd,
    const float* __restrict__ Wp, const float* __restrict__ bp,
    float* __restrict__ out) {
  __shared__ float dw[VT][68];              // 272B rows: 16B-aligned, quad (vl+q)%8 balanced
  __shared__ int   sidx[VT * SN];           // this block's 576 gather indices
  __shared__ float swdT[SN * CIN];          // Wd transposed [s][c]
  int t  = threadIdx.x;
  int b  = blockIdx.x & 7;                  // XCD-pinned batch
  int v0 = (blockIdx.x >> 3) * VT;

  for (int i = t; i < VT * SN; i += 256) {  // 576 coalesced loads each
    sidx[i] = indices[v0 * SN + i];
    int c = i / SN, s = i - c * SN;         // Wd flat idx i = c*SN + s
    swdT[s * CIN + c] = Wd[i];
  }
  __syncthreads();

  // ---- Phase A ----
  int g = t >> 4, l = t & 15, c4 = l * 4;
  f32x2 wd01[SN], wd23[SN];                 // 36 regs, as in round-0 wd4 table
#pragma unroll
  for (int s = 0; s < SN; ++s) {
    f32x4 w4 = *(const f32x4*)&swdT[s * CIN + c4];
    wd01[s] = (f32x2){w4.x, w4.y};
    wd23[s] = (f32x2){w4.z, w4.w};
  }
  f32x4 bd4 = *(const f32x4*)(bd + c4);
  const uint2* pbu = (const uint2*)(pooled + (size_t)(b << 14) * CIN);

#pragma unroll
  for (int vi = 0; vi < 4; ++vi) {
    int vl = g + vi * 16;
    int us[SN];
#pragma unroll
    for (int s = 0; s < SN; ++s) us[s] = sidx[vl * SN + s];  // group-broadcast reads
    f32x2 a01 = (f32x2){bd4.x, bd4.y};
    f32x2 a23 = (f32x2){bd4.z, bd4.w};
#pragma unroll
    for (int s = 0; s < SN; ++s) {
      uint2 hu = pbu[us[s] * 16 + l];       // 8B of bf16 (4 channels), L2-resident
      f32x2 p01 = (f32x2){__uint_as_float(hu.x << 16),
                          __uint_as_float(hu.x & 0xFFFF0000u)};
      f32x2 p23 = (f32x2){__uint_as_float(hu.y << 16),
                          __uint_as_float(hu.y & 0xFFFF0000u)};
      a01 += wd01[s] * p01;                 // packed-pair FMA
      a23 += wd23[s] * p23;
    }
    *(f32x4*)&dw[vl][c4] = (f32x4){a01.x, a01.y, a23.x, a23.y};
  }
  __syncthreads();

  // ---- Phase B: even/odd-channel float2 partials ----
  int vl = t & 63;
  int w  = t >> 6;
  int ob = __builtin_amdgcn_readfirstlane(w * 8);   // wave-uniform o-block
  const float* wpo = Wp + ob * CIN;
  f32x2 acc2[8];
#pragma unroll
  for (int oo = 0; oo < 8; ++oo) acc2[oo] = (f32x2){0.f, 0.f};
#pragma unroll
  for (int q = 0; q < 16; ++q) {
    f32x4 d4 = *(const f32x4*)&dw[vl][q * 4];       // ds_read_b128, balanced banks
    f32x2 dlo = (f32x2){d4.x, d4.y};
    f32x2 dhi = (f32x2){d4.z, d4.w};
#pragma unroll
    for (int oo = 0; oo < 8; ++oo) {
      f32x2 w0 = *(const f32x2*)(wpo + oo * CIN + q * 4);     // SGPR pairs (uniform)
      f32x2 w1 = *(const f32x2*)(wpo + oo * CIN + q * 4 + 2);
      acc2[oo] += dlo * w0;                 // v_pk_fma_f32-shaped
      acc2[oo] += dhi * w1;
    }
  }
  float* op = out + (size_t)((b << 14) + v0 + vl) * COUT + ob;
  f32x4 r0, r1;
  r0.x = fmaxf(acc2[0].x + acc2[0].y + bp[ob + 0], 0.f);
  r0.y = fmaxf(acc2[1].x + acc2[1].y + bp[ob + 1], 0.f);
  r0.z = fmaxf(acc2[2].x + acc2[2].y + bp[ob + 2], 0.f);
  r0.w = fmaxf(acc2[3].x + acc2[3].y + bp[ob + 3], 0.f);
  r1.x = fmaxf(acc2[4].x + acc2[4].y + bp[ob + 4], 0.f);
  r1.y = fmaxf(acc2[5].x + acc2[5].y + bp[ob + 5], 0.f);
  r1.z = fmaxf(acc2[6].x + acc2[6].y + bp[ob + 6], 0.f);
  r1.w = fmaxf(acc2[7].x + acc2[7].y + bp[ob + 7], 0.f);
  *(f32x4*)op = r0;
  *(f32x4*)(op + 4) = r1;
}

extern "C" void kernel_launch(void* const* d_in, const int* in_sizes, int n_in,
                              void* d_out, int out_size, void* d_ws, size_t ws_size,
                              hipStream_t stream) {
  const float* x    = (const float*)d_in[0];
  const int*   tc   = (const int*)d_in[2];
  const float* tv   = (const float*)d_in[3];
  const int*   rm   = (const int*)d_in[4];
  const int*   idx  = (const int*)d_in[5];
  const float* Wd   = (const float*)d_in[6];
  const float* bd   = (const float*)d_in[7];
  const float* Wp   = (const float*)d_in[8];
  const float* bp   = (const float*)d_in[9];
  float* out = (float*)d_out;
  unsigned short* pooled = (unsigned short*)d_ws;   // 16 MiB bf16

  pool_kernel<<<BATCH * (VOUTN / UPB), 256, 0, stream>>>(x, tc, tv, rm, pooled);
  dwpw_kernel<<<BATCH * (VOUTN / VT), 256, 0, stream>>>(pooled, idx, Wd, bd, Wp, bp, out);
}